// Round 21
// baseline (1753.212 us; speedup 1.0000x reference)
//
#include <hip/hip_runtime.h>

#define B_ 32
#define T_ 6
#define C_ 128
#define H_ 32
#define W_ 32
#define HW_ (H_ * W_)
#define CHW_ (C_ * H_ * W_)
#define NIMG_ (B_ * T_)       // 192
#define WELEM_ (C_ * C_ * 9)  // 147456
#define KTOT_ (C_ * 9)        // 1152 contraction length
#define PRE_KC 192            // OpenBLAS SKYLAKEX SGEMM_Q: 6 equal panels of 192

// Uncontractable fp32 add (separate IEEE rounding: panel joins, bias, scan).
__device__ __forceinline__ float add_rn_hw(float a, float b) {
    float d;
    asm volatile("v_add_f32 %0, %1, %2" : "=v"(d) : "v"(a), "v"(b));
    return d;
}

// ---------------------------------------------------------------------------
// Pre-conv weights: [O, I, 3, 3] -> [k][O] with k = (kh*3 + kw)*C + ci
// (NHWC patch linearization: kh outer, kw middle, ci fastest)
__global__ void transpose_w_kio_kernel(const float* __restrict__ w,
                                       float* __restrict__ wt) {
    int idx = blockIdx.x * blockDim.x + threadIdx.x;
    if (idx >= WELEM_) return;
    int o  = idx / (C_ * 9);
    int ci = (idx % (C_ * 9)) / 9;
    int kt = idx % 9;          // kh*3 + kw  (row-major taps)
    wt[(size_t)(kt * C_ + ci) * C_ + o] = w[idx];
}

// Post-conv weights: [O, I, 3, 3] -> [I, 3, 3, O] (fast layout, order-free)
__global__ void transpose_w_i33o_kernel(const float* __restrict__ w,
                                        float* __restrict__ wt) {
    int idx = blockIdx.x * blockDim.x + threadIdx.x;
    if (idx >= WELEM_) return;
    int o  = idx / (C_ * 9);
    int ci = (idx % (C_ * 9)) / 9;
    int kt = idx % 9;
    wt[(size_t)(ci * 9 + kt) * C_ + o] = w[idx];
}

// ---------------------------------------------------------------------------
// Pre-conv replicating NHWC-im2col + OpenBLAS SKYLAKEX sgemm (FMA, Q=192):
//   tot = 0
//   for each of 6 panels (k in [p*192, (p+1)*192)):
//       sub = 0
//       for k in panel (k = (kh*3+kw)*128 + ci, ci fastest):
//           sub = fmaf(x, w, sub)       // single-rounded FMA micro-kernel
//       tot = add(tot, sub)             // C += panel (one rounded fp32 add)
//   y = clamp(add(tot, bias), 0, alpha)
__global__ __launch_bounds__(256)
void conv_pre_blas_kernel(const float* __restrict__ in,   // [N, C, H, W]
                          const float* __restrict__ wt,   // [k][O]
                          const float* __restrict__ bias, // [O]
                          const float* __restrict__ alpha_p,
                          float* __restrict__ out) {      // [N, C, H, W]
    __shared__ float xs[C_ * 3 * 34];

    const int blk = blockIdx.x;      // n * H + h
    const int n = blk / H_;
    const int h = blk % H_;
    const int tid = threadIdx.x;

    // ---- stage 3 rows (h-1, h, h+1) of all 128 channels into LDS ----
    const float* inbase = in + (size_t)n * CHW_;
    for (int i = tid; i < C_ * 3 * 8; i += 256) {
        int c  = i / 24;
        int rr = (i % 24) / 8;
        int w4 = i % 8;
        int hh = h + rr - 1;
        float4 v = make_float4(0.f, 0.f, 0.f, 0.f);
        if (hh >= 0 && hh < H_) {
            v = *reinterpret_cast<const float4*>(inbase + c * HW_ + hh * W_ + w4 * 4);
        }
        float* dst = &xs[(c * 3 + rr) * 34 + 1 + w4 * 4];
        dst[0] = v.x; dst[1] = v.y; dst[2] = v.z; dst[3] = v.w;
    }
    for (int i = tid; i < C_ * 3 * 2; i += 256) {
        int cr = i >> 1;
        int side = i & 1;
        xs[cr * 34 + side * 33] = 0.f;
    }
    __syncthreads();

    const int co = (tid >> 3) * 4;   // c_out base
    const int wb = (tid & 7) * 4;    // w base

    float tot[4][4];
#pragma unroll
    for (int j = 0; j < 4; ++j)
#pragma unroll
        for (int q = 0; q < 4; ++q) tot[j][q] = 0.f;

    // ROW-major taps: kt = kh*3 + kw
    const int tap_row[9] = {0, 0, 0, 1, 1, 1, 2, 2, 2};
    const int tap_col[9] = {0, 1, 2, 0, 1, 2, 0, 1, 2};

    for (int pstart = 0; pstart < KTOT_; pstart += PRE_KC) {
        const int pend = (pstart + PRE_KC < KTOT_) ? (pstart + PRE_KC) : KTOT_;

        float sub[4][4];
#pragma unroll
        for (int j = 0; j < 4; ++j)
#pragma unroll
            for (int q = 0; q < 4; ++q) sub[j][q] = 0.f;

        int k = pstart;
        while (k < pend) {
            const int kt  = k >> 7;           // tap index 0..8
            const int ci0 = k & 127;
            int cnt = 128 - ci0;
            if (cnt > pend - k) cnt = pend - k;

            const float* xbase = &xs[tap_row[kt] * 34 + wb + tap_col[kt] + ci0 * 102];
            const float* wp = wt + (size_t)k * C_ + co;
            for (int c = 0; c < cnt; ++c) {
                float4 wv = *reinterpret_cast<const float4*>(wp);
                const float* xp = xbase + c * 102;
                float x0 = xp[0], x1 = xp[1], x2 = xp[2], x3 = xp[3];
#pragma unroll
                for (int j = 0; j < 4; ++j) {
                    float wj = (&wv.x)[j];
                    // single-rounded FMA chain (vfmadd micro-kernel)
                    sub[j][0] = fmaf(x0, wj, sub[j][0]);
                    sub[j][1] = fmaf(x1, wj, sub[j][1]);
                    sub[j][2] = fmaf(x2, wj, sub[j][2]);
                    sub[j][3] = fmaf(x3, wj, sub[j][3]);
                }
                wp += C_;
            }
            k += cnt;
        }

        // panel join: C += panel (one rounded add; first join exact vs 0)
#pragma unroll
        for (int j = 0; j < 4; ++j)
#pragma unroll
            for (int q = 0; q < 4; ++q) tot[j][q] = add_rn_hw(tot[j][q], sub[j][q]);
    }

    const float alpha = *alpha_p;
    float* outbase = out + (size_t)n * CHW_ + (size_t)h * W_ + wb;
#pragma unroll
    for (int j = 0; j < 4; ++j) {
        float bj = bias[co + j];
        float4 v;
#pragma unroll
        for (int q = 0; q < 4; ++q) {
            float y = add_rn_hw(tot[j][q], bj);       // bias AFTER the sum
            y = fminf(fmaxf(y, 0.f), alpha);          // clamp, fp32
            (&v.x)[q] = y;
        }
        *reinterpret_cast<float4*>(outbase + (size_t)(co + j) * HW_) = v;
    }
}

// ---------------------------------------------------------------------------
// Spiking scan over T, fp32. With thr = 1.0 and sp,inh in {0,1} every product
// is exactly representable; the only rounding step is mem + xt (hard add).
__global__ __launch_bounds__(256)
void spike_scan_kernel(float* __restrict__ ybuf,
                       const float* __restrict__ alpha_p) {
    int idx = blockIdx.x * blockDim.x + threadIdx.x;   // over B*C*H*W
    if (idx >= B_ * CHW_) return;
    int b = idx / CHW_;
    int r = idx % CHW_;
    const float thr = *alpha_p;

    float mem = 0.5f * thr;
    float ss = 0.f;
    size_t base = (size_t)b * T_ * CHW_ + r;
#pragma unroll
    for (int t = 0; t < T_; ++t) {
        float xt = ybuf[base + (size_t)t * CHW_];
        mem = add_rn_hw(mem, xt);                 // the only rounding step
        float sp = (mem >= thr) ? 1.f : 0.f;
        mem = mem - thr * sp;
        ss = ss + sp;
        float inh = ((mem <= -0.001f) && (ss > 0.f)) ? 1.f : 0.f;
        mem = mem + thr * inh;
        ss = ss - inh;
        ybuf[base + (size_t)t * CHW_] = (sp - inh) * thr;
    }
}

// ---------------------------------------------------------------------------
// Post-conv fp32 (inputs are exact {0, thr} spikes; order-free, fast layout).
__global__ __launch_bounds__(256)
void conv3x3_post_kernel(const float* __restrict__ in,   // [N, C, H, W]
                         const float* __restrict__ wt,   // [I, 3, 3, O]
                         const float* __restrict__ bias, // [O]
                         float* __restrict__ out) {      // [N, C, H, W]
    __shared__ float xs[C_ * 3 * 34];

    const int blk = blockIdx.x;
    const int n = blk / H_;
    const int h = blk % H_;
    const int tid = threadIdx.x;

    const float* inbase = in + (size_t)n * CHW_;
    for (int i = tid; i < C_ * 3 * 8; i += 256) {
        int c  = i / 24;
        int rr = (i % 24) / 8;
        int w4 = i % 8;
        int hh = h + rr - 1;
        float4 v = make_float4(0.f, 0.f, 0.f, 0.f);
        if (hh >= 0 && hh < H_) {
            v = *reinterpret_cast<const float4*>(inbase + c * HW_ + hh * W_ + w4 * 4);
        }
        float* dst = &xs[(c * 3 + rr) * 34 + 1 + w4 * 4];
        dst[0] = v.x; dst[1] = v.y; dst[2] = v.z; dst[3] = v.w;
    }
    for (int i = tid; i < C_ * 3 * 2; i += 256) {
        int cr = i >> 1;
        int side = i & 1;
        xs[cr * 34 + side * 33] = 0.f;
    }
    __syncthreads();

    const int co = (tid >> 3) * 4;
    const int wb = (tid & 7) * 4;

    float4 bv = *reinterpret_cast<const float4*>(bias + co);
    float acc[4][4];
#pragma unroll
    for (int j = 0; j < 4; ++j)
#pragma unroll
        for (int q = 0; q < 4; ++q) acc[j][q] = (&bv.x)[j];

    for (int ci = 0; ci < C_; ++ci) {
        const float* xrow = &xs[ci * 3 * 34];
        const float* wrow = &wt[(size_t)ci * 9 * C_ + co];
#pragma unroll
        for (int r = 0; r < 3; ++r) {
            float xv[6];
            const float* p = xrow + r * 34 + wb;
#pragma unroll
            for (int q = 0; q < 6; ++q) xv[q] = p[q];
#pragma unroll
            for (int dw = 0; dw < 3; ++dw) {
                float4 wv = *reinterpret_cast<const float4*>(wrow + (size_t)(r * 3 + dw) * C_);
#pragma unroll
                for (int j = 0; j < 4; ++j) {
                    float wj = (&wv.x)[j];
#pragma unroll
                    for (int q = 0; q < 4; ++q) {
                        acc[j][q] = fmaf(xv[q + dw], wj, acc[j][q]);
                    }
                }
            }
        }
    }

    float* outbase = out + (size_t)n * CHW_ + (size_t)h * W_ + wb;
#pragma unroll
    for (int j = 0; j < 4; ++j) {
        float4 v;
#pragma unroll
        for (int q = 0; q < 4; ++q) (&v.x)[q] = acc[j][q];
        *reinterpret_cast<float4*>(outbase + (size_t)(co + j) * HW_) = v;
    }
}

// ---------------------------------------------------------------------------
extern "C" void kernel_launch(void* const* d_in, const int* in_sizes, int n_in,
                              void* d_out, int out_size, void* d_ws, size_t ws_size,
                              hipStream_t stream) {
    const float* x       = (const float*)d_in[0];  // [B,T,C,H,W]
    const float* w_pre   = (const float*)d_in[1];  // [C,C,3,3]
    const float* b_pre   = (const float*)d_in[2];  // [C]
    const float* alpha_p = (const float*)d_in[3];  // scalar
    const float* w_post  = (const float*)d_in[4];  // [C,C,3,3]
    const float* b_post  = (const float*)d_in[5];  // [C]
    float* out = (float*)d_out;

    // workspace layout
    char* ws = (char*)d_ws;
    float* wt_pre  = (float*)ws;                       // 589,824 B
    float* wt_post = (float*)(ws + (1 << 20));         // 589,824 B
    float* ybuf    = (float*)(ws + (2 << 20));         // ~100.7 MB

    {
        dim3 g((WELEM_ + 255) / 256), b(256);
        transpose_w_kio_kernel<<<g, b, 0, stream>>>(w_pre, wt_pre);
        transpose_w_i33o_kernel<<<g, b, 0, stream>>>(w_post, wt_post);
    }
    // 1) pre-conv (rm taps, FMA, Q=192 x6 equal panels) + bias + clip
    {
        dim3 g(NIMG_ * H_), b(256);   // 6144 blocks
        conv_pre_blas_kernel<<<g, b, 0, stream>>>(x, wt_pre, b_pre, alpha_p, ybuf);
    }
    // 2) spiking scan fp32 (in place)
    {
        int total = B_ * CHW_;
        dim3 g(total / 256), b(256);
        spike_scan_kernel<<<g, b, 0, stream>>>(ybuf, alpha_p);
    }
    // 3) post-conv fp32 -> out
    {
        dim3 g(NIMG_ * H_), b(256);
        conv3x3_post_kernel<<<g, b, 0, stream>>>(ybuf, wt_post, b_post, out);
    }
}

// Round 22
// 1041.007 us; speedup vs baseline: 1.6841x; 1.6841x over previous
//
#include <hip/hip_runtime.h>
#include <hip/hip_bf16.h>

#define B_ 32
#define T_ 6
#define C_ 128
#define H_ 32
#define W_ 32
#define HW_ (H_ * W_)
#define CHW_ (C_ * H_ * W_)
#define NIMG_ (B_ * T_)       // 192
#define WELEM_ (C_ * C_ * 9)  // 147456
#define KTOT_ (C_ * 9)        // 1152 contraction length
#define PRE_KC 192            // OpenBLAS SKYLAKEX SGEMM_Q: 6 equal panels (VERIFIED R21)

typedef __attribute__((ext_vector_type(8))) short bf16x8;
typedef __attribute__((ext_vector_type(4))) float f32x4;

// Uncontractable fp32 add (separate IEEE rounding: panel joins, bias, scan).
__device__ __forceinline__ float add_rn_hw(float a, float b) {
    float d;
    asm volatile("v_add_f32 %0, %1, %2" : "=v"(d) : "v"(a), "v"(b));
    return d;
}

__device__ __forceinline__ unsigned short f2bf(float x) {
    __hip_bfloat16 h = __float2bfloat16(x);
    return *reinterpret_cast<unsigned short*>(&h);
}

// ---------------------------------------------------------------------------
// Pre-conv weights: [O, I, 3, 3] -> [k][O] with k = (kh*3 + kw)*C + ci
__global__ void transpose_w_kio_kernel(const float* __restrict__ w,
                                       float* __restrict__ wt) {
    int idx = blockIdx.x * blockDim.x + threadIdx.x;
    if (idx >= WELEM_) return;
    int o  = idx / (C_ * 9);
    int ci = (idx % (C_ * 9)) / 9;
    int kt = idx % 9;          // kh*3 + kw  (row-major taps)
    wt[(size_t)(kt * C_ + ci) * C_ + o] = w[idx];
}

// ---------------------------------------------------------------------------
// Post-conv weights -> MFMA fragment order, split w = hi + lo (bf16 pair).
// idx = ((chunk*8 + ct)*64 + lane)*8 + j ; chunk = kt*4 + cb
// co = ct*16 + (lane&15), ci = cb*32 + (lane>>4)*8 + j
__global__ void pack_w_post_kernel(const float* __restrict__ w,
                                   unsigned short* __restrict__ hi,
                                   unsigned short* __restrict__ lo) {
    int idx = blockIdx.x * blockDim.x + threadIdx.x;
    if (idx >= WELEM_) return;
    int j     = idx & 7;
    int lane  = (idx >> 3) & 63;
    int ct    = (idx >> 9) & 7;
    int chunk = idx >> 12;            // 0..35
    int kt = chunk >> 2;
    int cb = chunk & 3;
    int co = ct * 16 + (lane & 15);
    int ci = cb * 32 + ((lane >> 4) << 3) + j;
    float v = w[(size_t)(co * C_ + ci) * 9 + kt];
    unsigned short h = f2bf(v);
    __hip_bfloat16 hb = *reinterpret_cast<__hip_bfloat16*>(&h);
    float rest = v - __bfloat162float(hb);
    hi[idx] = h;
    lo[idx] = f2bf(rest);
}

// ---------------------------------------------------------------------------
// Pre-conv replicating NHWC-im2col + OpenBLAS SKYLAKEX sgemm (FMA, Q=192).
// VERIFIED bit-exact vs the np reference in round 21 — DO NOT CHANGE ORDER.
__global__ __launch_bounds__(256)
void conv_pre_blas_kernel(const float* __restrict__ in,   // [N, C, H, W]
                          const float* __restrict__ wt,   // [k][O]
                          const float* __restrict__ bias, // [O]
                          const float* __restrict__ alpha_p,
                          float* __restrict__ out) {      // [N, C, H, W]
    __shared__ float xs[C_ * 3 * 34];

    const int blk = blockIdx.x;      // n * H + h
    const int n = blk / H_;
    const int h = blk % H_;
    const int tid = threadIdx.x;

    const float* inbase = in + (size_t)n * CHW_;
    for (int i = tid; i < C_ * 3 * 8; i += 256) {
        int c  = i / 24;
        int rr = (i % 24) / 8;
        int w4 = i % 8;
        int hh = h + rr - 1;
        float4 v = make_float4(0.f, 0.f, 0.f, 0.f);
        if (hh >= 0 && hh < H_) {
            v = *reinterpret_cast<const float4*>(inbase + c * HW_ + hh * W_ + w4 * 4);
        }
        float* dst = &xs[(c * 3 + rr) * 34 + 1 + w4 * 4];
        dst[0] = v.x; dst[1] = v.y; dst[2] = v.z; dst[3] = v.w;
    }
    for (int i = tid; i < C_ * 3 * 2; i += 256) {
        int cr = i >> 1;
        int side = i & 1;
        xs[cr * 34 + side * 33] = 0.f;
    }
    __syncthreads();

    const int co = (tid >> 3) * 4;   // c_out base
    const int wb = (tid & 7) * 4;    // w base

    float tot[4][4];
#pragma unroll
    for (int j = 0; j < 4; ++j)
#pragma unroll
        for (int q = 0; q < 4; ++q) tot[j][q] = 0.f;

    const int tap_row[9] = {0, 0, 0, 1, 1, 1, 2, 2, 2};
    const int tap_col[9] = {0, 1, 2, 0, 1, 2, 0, 1, 2};

    for (int pstart = 0; pstart < KTOT_; pstart += PRE_KC) {
        const int pend = (pstart + PRE_KC < KTOT_) ? (pstart + PRE_KC) : KTOT_;

        float sub[4][4];
#pragma unroll
        for (int j = 0; j < 4; ++j)
#pragma unroll
            for (int q = 0; q < 4; ++q) sub[j][q] = 0.f;

        int k = pstart;
        while (k < pend) {
            const int kt  = k >> 7;
            const int ci0 = k & 127;
            int cnt = 128 - ci0;
            if (cnt > pend - k) cnt = pend - k;

            const float* xbase = &xs[tap_row[kt] * 34 + wb + tap_col[kt] + ci0 * 102];
            const float* wp = wt + (size_t)k * C_ + co;
            for (int c = 0; c < cnt; ++c) {
                float4 wv = *reinterpret_cast<const float4*>(wp);
                const float* xp = xbase + c * 102;
                float x0 = xp[0], x1 = xp[1], x2 = xp[2], x3 = xp[3];
#pragma unroll
                for (int j = 0; j < 4; ++j) {
                    float wj = (&wv.x)[j];
                    sub[j][0] = fmaf(x0, wj, sub[j][0]);
                    sub[j][1] = fmaf(x1, wj, sub[j][1]);
                    sub[j][2] = fmaf(x2, wj, sub[j][2]);
                    sub[j][3] = fmaf(x3, wj, sub[j][3]);
                }
                wp += C_;
            }
            k += cnt;
        }

#pragma unroll
        for (int j = 0; j < 4; ++j)
#pragma unroll
            for (int q = 0; q < 4; ++q) tot[j][q] = add_rn_hw(tot[j][q], sub[j][q]);
    }

    const float alpha = *alpha_p;
    float* outbase = out + (size_t)n * CHW_ + (size_t)h * W_ + wb;
#pragma unroll
    for (int j = 0; j < 4; ++j) {
        float bj = bias[co + j];
        float4 v;
#pragma unroll
        for (int q = 0; q < 4; ++q) {
            float y = add_rn_hw(tot[j][q], bj);
            y = fminf(fmaxf(y, 0.f), alpha);
            (&v.x)[q] = y;
        }
        *reinterpret_cast<float4*>(outbase + (size_t)(co + j) * HW_) = v;
    }
}

// ---------------------------------------------------------------------------
// Spiking scan over T, fp32 (bit-exact — VERIFIED round 21, unchanged).
__global__ __launch_bounds__(256)
void spike_scan_kernel(float* __restrict__ ybuf,
                       const float* __restrict__ alpha_p) {
    int idx = blockIdx.x * blockDim.x + threadIdx.x;
    if (idx >= B_ * CHW_) return;
    int b = idx / CHW_;
    int r = idx % CHW_;
    const float thr = *alpha_p;

    float mem = 0.5f * thr;
    float ss = 0.f;
    size_t base = (size_t)b * T_ * CHW_ + r;
#pragma unroll
    for (int t = 0; t < T_; ++t) {
        float xt = ybuf[base + (size_t)t * CHW_];
        mem = add_rn_hw(mem, xt);
        float sp = (mem >= thr) ? 1.f : 0.f;
        mem = mem - thr * sp;
        ss = ss + sp;
        float inh = ((mem <= -0.001f) && (ss > 0.f)) ? 1.f : 0.f;
        mem = mem + thr * inh;
        ss = ss - inh;
        ybuf[base + (size_t)t * CHW_] = (sp - inh) * thr;
    }
}

// ---------------------------------------------------------------------------
// Post-conv via bf16 MFMA, hi+lo weight split (residual ~1e-5 << bf16 ulp).
// Block = (n, h2): 128 co x 64 px (2 h-rows x 32 w). 4 waves x (32co x 64px).
__global__ __launch_bounds__(256)
void conv_post_mfma_kernel(const float* __restrict__ ybuf,
                           const unsigned short* __restrict__ pk_hi,
                           const unsigned short* __restrict__ pk_lo,
                           const float* __restrict__ bias,
                           float* __restrict__ out) {
    __shared__ unsigned short sp[4 * 34 * 136];   // 36992 B, bf16 spikes

    const int n  = blockIdx.x >> 4;
    const int h2 = blockIdx.x & 15;
    const int h0 = h2 * 2;
    const int tid = threadIdx.x;

    // ---- stage 4 input rows (h0-1..h0+2), 34 w (halo), 128 ci as bf16 ----
    for (int p = tid; p < 512; p += 256) {       // p = row*128 + ci
        int row = p >> 7, ci = p & 127;
        int gh = h0 - 1 + row;
        unsigned short* dst = &sp[(row * 34) * 136 + ci];
        if (gh >= 0 && gh < H_) {
            const float* src = ybuf + (((size_t)n * C_ + ci) * H_ + gh) * W_;
            dst[0] = 0;                          // w = -1 halo
#pragma unroll
            for (int w4 = 0; w4 < 8; ++w4) {
                float4 v = *reinterpret_cast<const float4*>(src + w4 * 4);
                dst[(1 + w4 * 4 + 0) * 136] = f2bf(v.x);
                dst[(1 + w4 * 4 + 1) * 136] = f2bf(v.y);
                dst[(1 + w4 * 4 + 2) * 136] = f2bf(v.z);
                dst[(1 + w4 * 4 + 3) * 136] = f2bf(v.w);
            }
            dst[33 * 136] = 0;                   // w = 32 halo
        } else {
#pragma unroll
            for (int w = 0; w < 34; ++w) dst[w * 136] = 0;
        }
    }
    __syncthreads();

    const int wave = tid >> 6, lane = tid & 63;
    const int l15 = lane & 15, l4 = lane >> 4;

    f32x4 acc[2][4];
#pragma unroll
    for (int ct = 0; ct < 2; ++ct)
#pragma unroll
        for (int t = 0; t < 4; ++t) acc[ct][t] = (f32x4){0.f, 0.f, 0.f, 0.f};

    for (int kt = 0; kt < 9; ++kt) {
        const int tr = kt / 3, tc = kt % 3;
#pragma unroll
        for (int cb = 0; cb < 4; ++cb) {
            const int chunk = kt * 4 + cb;
            // B fragments: lane reads 8 consecutive ci (16B) at its px column
            bf16x8 bf[4];
#pragma unroll
            for (int t = 0; t < 4; ++t) {
                int rsp = (t >> 1) + tr;
                int wsp = (t & 1) * 16 + l15 + tc;
                bf[t] = *reinterpret_cast<const bf16x8*>(
                    &sp[(rsp * 34 + wsp) * 136 + cb * 32 + l4 * 8]);
            }
            // A fragments: direct 16B loads from packed weights
            const unsigned short* pa = pk_hi + ((size_t)(chunk * 8 + wave * 2) * 64 + lane) * 8;
            const unsigned short* pl = pk_lo + ((size_t)(chunk * 8 + wave * 2) * 64 + lane) * 8;
            bf16x8 ah0 = *reinterpret_cast<const bf16x8*>(pa);
            bf16x8 ah1 = *reinterpret_cast<const bf16x8*>(pa + 512);
            bf16x8 al0 = *reinterpret_cast<const bf16x8*>(pl);
            bf16x8 al1 = *reinterpret_cast<const bf16x8*>(pl + 512);
#pragma unroll
            for (int t = 0; t < 4; ++t) {
                acc[0][t] = __builtin_amdgcn_mfma_f32_16x16x32_bf16(ah0, bf[t], acc[0][t], 0, 0, 0);
                acc[1][t] = __builtin_amdgcn_mfma_f32_16x16x32_bf16(ah1, bf[t], acc[1][t], 0, 0, 0);
                acc[0][t] = __builtin_amdgcn_mfma_f32_16x16x32_bf16(al0, bf[t], acc[0][t], 0, 0, 0);
                acc[1][t] = __builtin_amdgcn_mfma_f32_16x16x32_bf16(al1, bf[t], acc[1][t], 0, 0, 0);
            }
        }
    }

    // ---- epilogue: C/D layout col=lane&15, row=(lane>>4)*4+reg ----
#pragma unroll
    for (int ct = 0; ct < 2; ++ct) {
#pragma unroll
        for (int reg = 0; reg < 4; ++reg) {
            int co = wave * 32 + ct * 16 + l4 * 4 + reg;
            float bv = bias[co];
#pragma unroll
            for (int t = 0; t < 4; ++t) {
                int hh = h0 + (t >> 1);
                int ww = (t & 1) * 16 + l15;
                out[(((size_t)n * C_ + co) * H_ + hh) * W_ + ww] = acc[ct][t][reg] + bv;
            }
        }
    }
}

// ---------------------------------------------------------------------------
extern "C" void kernel_launch(void* const* d_in, const int* in_sizes, int n_in,
                              void* d_out, int out_size, void* d_ws, size_t ws_size,
                              hipStream_t stream) {
    const float* x       = (const float*)d_in[0];  // [B,T,C,H,W]
    const float* w_pre   = (const float*)d_in[1];  // [C,C,3,3]
    const float* b_pre   = (const float*)d_in[2];  // [C]
    const float* alpha_p = (const float*)d_in[3];  // scalar
    const float* w_post  = (const float*)d_in[4];  // [C,C,3,3]
    const float* b_post  = (const float*)d_in[5];  // [C]
    float* out = (float*)d_out;

    // workspace layout
    char* ws = (char*)d_ws;
    float*          wt_pre = (float*)ws;                        // 589,824 B
    unsigned short* pk_hi  = (unsigned short*)(ws + 655360);    // 294,912 B
    unsigned short* pk_lo  = (unsigned short*)(ws + 983040);    // 294,912 B
    float*          ybuf   = (float*)(ws + (2 << 20));          // ~100.7 MB

    {
        dim3 g((WELEM_ + 255) / 256), b(256);
        transpose_w_kio_kernel<<<g, b, 0, stream>>>(w_pre, wt_pre);
        pack_w_post_kernel<<<g, b, 0, stream>>>(w_post, pk_hi, pk_lo);
    }
    // 1) pre-conv (rm taps, FMA, Q=192 x6 equal panels) + bias + clip  [EXACT]
    {
        dim3 g(NIMG_ * H_), b(256);
        conv_pre_blas_kernel<<<g, b, 0, stream>>>(x, wt_pre, b_pre, alpha_p, ybuf);
    }
    // 2) spiking scan fp32 (in place)  [EXACT]
    {
        int total = B_ * CHW_;
        dim3 g(total / 256), b(256);
        spike_scan_kernel<<<g, b, 0, stream>>>(ybuf, alpha_p);
    }
    // 3) post-conv via bf16 MFMA (hi+lo split) -> out
    {
        dim3 g(NIMG_ * 16), b(256);   // 3072 blocks: (n, h/2)
        conv_post_mfma_kernel<<<g, b, 0, stream>>>(ybuf, pk_hi, pk_lo, b_post, out);
    }
}